// Round 2
// baseline (155.357 us; speedup 1.0000x reference)
//
#include <hip/hip_runtime.h>
#include <hip/hip_bf16.h>
#include <math.h>

// FieldTypedProjector: per-token Fourier features -> per-kind 2-layer MLP (exact GELU)
//   out[t] = W2[k]^T gelu(W1[k]^T ff(v_t) + b1[k]) + b2[k] + kind_emb[k]
// R8: (a) memset dispatch deleted — g_counts zeroed by the LAST fproj block via
//     an atomic ticket (g_done). First call relies on static zero-init of
//     __device__ globals; later calls on the previous fproj's end-of-dispatch
//     zeroing (stream-ordered before the next prep). Output bitwise invariant.
// (b) fproj prologue MLP: GEMM1 B-frags + b1/b2/kind_emb bias loads hoisted
//     ABOVE the 64-v_sin Fourier phase so L2 latency hides under the
//     transcendental chain.
// Carried from R7: fused atomic bucketing in prep; M=64/512-thread fproj
// (160KB L2 B-traffic amortized over 64 tokens); cos via sin(x+0.25 rev).

#define NK 8
#define DM 256
#define TMAX 65536     // N*S = 32*2048
#define NBLK 256       // T/256 histogram blocks
#define W1PK 16384     // per-kind packed W1 elements (64*256)
#define W2PK 65536     // per-kind packed W2 elements (256*256)
#define LDSTRIDE 262   // prep slab stride

typedef __attribute__((ext_vector_type(8))) short   s16x8;
typedef __attribute__((ext_vector_type(8))) __bf16  bf16x8;
typedef __attribute__((ext_vector_type(4))) float   f32x4;
typedef __attribute__((ext_vector_type(2))) float   f32x2;

// Static device scratch — rewritten every call (never touches d_ws).
__device__ __align__(16) int g_counts[NK * 32];   // one counter per 128B line; zero-init
__device__ int   g_done;                          // fproj completion ticket; zero-init
__device__ int   g_bucket[(size_t)NK * TMAX];
__device__ __align__(16) short g_W1p[(size_t)NK * W1PK];
__device__ __align__(16) short g_W2p[(size_t)NK * W2PK];

static __device__ __forceinline__ short f2bf(float f) {
    __hip_bfloat16 h = __float2bfloat16(f);
    return __builtin_bit_cast(short, h);
}

// round-to-nearest-ish bf16 truncation (<=1 ulp bf16)
static __device__ __forceinline__ short pkbf(float f) {
    unsigned u = __builtin_bit_cast(unsigned, f);
    return (short)((u + 0x8000u) >> 16);
}

static __device__ __forceinline__ f32x4 mfma16(s16x8 a, s16x8 b, f32x4 c) {
    return __builtin_amdgcn_mfma_f32_16x16x32_bf16(
        __builtin_bit_cast(bf16x8, a), __builtin_bit_cast(bf16x8, b), c, 0, 0, 0);
}

// tanh-form GELU: x*sigmoid(1.59577(x+0.044715x^3)); |err| vs exact erf ~3e-4
static __device__ __forceinline__ float gelu_fast(float x) {
    float t1 = x * x;
    float m  = fmaf(0.0713548162726f, t1, 1.59576912161f);
    float z  = m * x;
    float e  = __expf(-z);
    return x * __frcp_rn(1.0f + e);
}

// ---------------- kernel A: weight pack (LDS-staged) + atomic bucket scatter --
__global__ __launch_bounds__(256) void prep_kernel(const float* __restrict__ W1,
                                                   const float* __restrict__ W2,
                                                   const int* __restrict__ kinds, int T) {
    const int tid = threadIdx.x;
    const int bid = blockIdx.x;
    if (bid < 80) {
        __shared__ float ld[32 * LDSTRIDE];
        const int isW1 = (bid >= 64);
        int kind, kt;
        if (isW1) { kind = (bid - 64) >> 1; kt = (bid - 64) & 1; }
        else      { kind = bid >> 3;        kt = bid & 7; }
        #pragma unroll
        for (int i = 0; i < 8; ++i) {
            int f = tid + i * 256;
            int row = f >> 6, col = (f & 63) * 4;
            int kk = kt * 32 + row;
            f32x4 v = (f32x4){0.f, 0.f, 0.f, 0.f};
            if (isW1) {
                if (kk < 48) v = *(const f32x4*)(W1 + ((size_t)kind * 48 + kk) * DM + col);
            } else {
                v = *(const f32x4*)(W2 + ((size_t)kind * DM + kk) * DM + col);
            }
            float* dst = &ld[row * LDSTRIDE + col];
            *(f32x2*)dst       = (f32x2){v[0], v[1]};
            *(f32x2*)(dst + 2) = (f32x2){v[2], v[3]};
        }
        __syncthreads();
        short* outp = isW1 ? (g_W1p + (size_t)kind * W1PK) : (g_W2p + (size_t)kind * W2PK);
        #pragma unroll
        for (int i = 0; i < 4; ++i) {
            int g = tid + i * 256;
            int ntile = g >> 6, l = g & 63;
            int kk0 = (l >> 4) * 8, n = ntile * 16 + (l & 15);
            s16x8 v;
            #pragma unroll
            for (int j = 0; j < 8; ++j) v[j] = f2bf(ld[(kk0 + j) * LDSTRIDE + n]);
            *(s16x8*)(outp + ((size_t)(kt * 16 + ntile) * 64 + l) * 8) = v;
        }
    } else {
        __shared__ int wcnt[4][NK];
        __shared__ int base_s[NK];
        const int b = bid - 80;
        const int wave = tid >> 6, lane = tid & 63;
        int t = b * 256 + tid;
        int k = (t < T) ? kinds[t] : -1;
        int rank = 0;
        #pragma unroll
        for (int kk = 0; kk < NK; ++kk) {
            unsigned long long m = __ballot(k == kk);
            if (lane == 0) wcnt[wave][kk] = __popcll(m);
            if (k == kk) rank = __popcll(m & ((1ull << lane) - 1ull));
        }
        __syncthreads();
        if (tid < NK) {
            int ws = 0;
            #pragma unroll
            for (int w = 0; w < 4; ++w) { int c = wcnt[w][tid]; wcnt[w][tid] = ws; ws += c; }
            base_s[tid] = atomicAdd(&g_counts[tid * 32], ws);
        }
        __syncthreads();
        if (k >= 0)
            g_bucket[(size_t)k * T + base_s[k] + wcnt[wave][k] + rank] = t;
    }
}

// last fproj block zeroes the counters for the NEXT graph iteration
static __device__ __forceinline__ void finish_ticket(int nblocks) {
    __threadfence();
    int old = atomicAdd(&g_done, 1);
    if (old == nblocks - 1) {
        g_done = 0;
        #pragma unroll
        for (int i = 0; i < NK; ++i) g_counts[i * 32] = 0;
        __threadfence();
    }
}

// ---------------- kernel B: fused MLP, 64-token tile of one kind --------------
__global__ __launch_bounds__(512, 4) void fproj_gemm(
    const float* __restrict__ values, const float* __restrict__ Bmat,
    const float* __restrict__ kind_emb, const float* __restrict__ b1,
    const float* __restrict__ b2, float* __restrict__ out, int T)
{
    // worklist mapping: block -> (kind, 64-token tile)
    int cnts[NK];
    #pragma unroll
    for (int i = 0; i < NK; ++i) cnts[i] = g_counts[i * 32];
    const int bid = blockIdx.x;
    const int tid = threadIdx.x;
    int k = -1, m0 = 0, cum = 0, cnt = 0;
    #pragma unroll
    for (int kk = 0; kk < NK; ++kk) {
        int tk = (cnts[kk] + 63) >> 6;
        if (k < 0 && bid < cum + tk) { k = kk; m0 = (bid - cum) * 64; cnt = cnts[kk]; }
        cum += tk;
    }
    if (k < 0) {
        if (tid == 0) finish_ticket((int)gridDim.x);
        return;
    }
    const int valid = min(64, cnt - m0);
    const int* buck = g_bucket + (size_t)k * T + m0;

    __shared__ short Hpack[16384];  // h 64x256 bf16, A-frag order: (kt2*4+mt)*512 + l*8 + j

    const int wv   = tid >> 6;          // 0..7, wave covers cols [wv*32, +32)
    const int lane = tid & 63;
    const int quad = lane >> 4;
    const int cl   = lane & 15;

    // ---- prologue prefetch: GEMM1 B-frags + biases issued BEFORE the sin
    // chain so their L2 latency hides under the transcendentals.
    const s16x8* B1p = (const s16x8*)(g_W1p + (size_t)k * W1PK);
    s16x8 bfp[2][2];
    #pragma unroll
    for (int kt = 0; kt < 2; ++kt)
        #pragma unroll
        for (int nt = 0; nt < 2; ++nt) bfp[kt][nt] = B1p[(kt * 16 + wv * 2 + nt) * 64 + lane];
    float bias1[2], addc[2];
    #pragma unroll
    for (int nt = 0; nt < 2; ++nt) {
        int c = wv * 32 + nt * 16 + cl;
        bias1[nt] = b1[k * DM + c];
        addc[nt]  = b2[k * DM + c] + kind_emb[k * DM + c];
    }

    // ---- Fourier features directly in A-frag registers for 4 row groups.
    // a-frag elem j, k-tile kt, row group mt: ff[m = mt*16 + cl][kk = kt*32 + quad*8 + j]
    //   kk<24: sin(2*pi*v*B[kk]); kk<48: cos(2*pi*v*B[kk-24]); else 0
    float vm[4];
    #pragma unroll
    for (int mt = 0; mt < 4; ++mt) {
        int row = mt * 16 + cl;
        vm[mt] = (row < valid) ? values[buck[row]] : 0.0f;
    }
    // per-thread band constants (mt-independent); cos(x)=sin(x+0.25 rev)
    float bb0[8], bb1[8];
    const float add0 = (quad == 3) ? 0.25f : 0.0f;
    #pragma unroll
    for (int j = 0; j < 8; ++j) {
        int b0 = (quad == 3) ? j : quad * 8 + j;       // kt=0: quads 0-2 sin, quad 3 cos
        bb0[j] = Bmat[b0];
        int b1i = min(8 * (quad + 1) + j, 23);         // kt=1: quads 0-1 cos, 2-3 zero
        bb1[j] = Bmat[b1i];
    }
    s16x8 a0[4], a1[4];
    #pragma unroll
    for (int mt = 0; mt < 4; ++mt) {
        float v = vm[mt];
        #pragma unroll
        for (int j = 0; j < 8; ++j) {
            float r0 = __builtin_amdgcn_fractf(fmaf(v, bb0[j], add0));
            a0[mt][j] = pkbf(__builtin_amdgcn_sinf(r0));
            float r1 = __builtin_amdgcn_fractf(fmaf(v, bb1[j], 0.25f));
            float c1 = __builtin_amdgcn_sinf(r1);
            a1[mt][j] = pkbf((quad < 2) ? c1 : 0.0f);
        }
    }

    // ---- GEMM1: [64 x 64] x [64 x 256], wave covers cols [wv*32, +32)
    f32x4 acc[4][2];
    #pragma unroll
    for (int mt = 0; mt < 4; ++mt)
        #pragma unroll
        for (int nt = 0; nt < 2; ++nt) acc[mt][nt] = (f32x4){0.f, 0.f, 0.f, 0.f};
    #pragma unroll
    for (int kt = 0; kt < 2; ++kt) {
        #pragma unroll
        for (int mt = 0; mt < 4; ++mt) {
            s16x8 a = kt ? a1[mt] : a0[mt];
            #pragma unroll
            for (int nt = 0; nt < 2; ++nt) acc[mt][nt] = mfma16(a, bfp[kt][nt], acc[mt][nt]);
        }
    }

    // ---- bias + GELU -> Hpack (A-frag layout for GEMM2)
    // C-layout source: lane holds H[m = mt*16 + quad*4 + r][c = wv*32 + nt*16 + cl]
    #pragma unroll
    for (int nt = 0; nt < 2; ++nt) {
        int c = wv * 32 + nt * 16 + cl;
        int kt2 = c >> 5, q2 = (c >> 3) & 3, j2 = c & 7;
        #pragma unroll
        for (int mt = 0; mt < 4; ++mt) {
            short* hp = Hpack + (kt2 * 4 + mt) * 512 + q2 * 128 + j2;
            #pragma unroll
            for (int r = 0; r < 4; ++r) {
                int m = quad * 4 + r;               // row within 16-row group
                float h = gelu_fast(acc[mt][nt][r] + bias1[nt]);
                hp[m * 8] = pkbf(h);
            }
        }
    }
    __syncthreads();

    // ---- GEMM2: [64 x 256] x [256 x 256], wave covers cols [wv*32, +32)
    f32x4 acc2[4][2];
    #pragma unroll
    for (int mt = 0; mt < 4; ++mt)
        #pragma unroll
        for (int nt = 0; nt < 2; ++nt) acc2[mt][nt] = (f32x4){0.f, 0.f, 0.f, 0.f};
    const s16x8* Hp  = (const s16x8*)Hpack;
    const s16x8* B2p = (const s16x8*)(g_W2p + (size_t)k * W2PK);
    #pragma unroll
    for (int kt = 0; kt < 8; ++kt) {
        s16x8 am[4];
        #pragma unroll
        for (int mt = 0; mt < 4; ++mt) am[mt] = Hp[(kt * 4 + mt) * 64 + lane];
        s16x8 bf[2];
        #pragma unroll
        for (int nt = 0; nt < 2; ++nt) bf[nt] = B2p[(kt * 16 + wv * 2 + nt) * 64 + lane];
        #pragma unroll
        for (int mt = 0; mt < 4; ++mt)
            #pragma unroll
            for (int nt = 0; nt < 2; ++nt) acc2[mt][nt] = mfma16(am[mt], bf[nt], acc2[mt][nt]);
    }

    // ---- epilogue: + b2 + kind_emb, scatter rows to out (nontemporal)
    #pragma unroll
    for (int mt = 0; mt < 4; ++mt)
        #pragma unroll
        for (int r = 0; r < 4; ++r) {
            int row = mt * 16 + quad * 4 + r;
            if (row < valid) {
                size_t ro = (size_t)buck[row] * DM;
                #pragma unroll
                for (int nt = 0; nt < 2; ++nt) {
                    int c = wv * 32 + nt * 16 + cl;
                    __builtin_nontemporal_store(acc2[mt][nt][r] + addc[nt], out + ro + c);
                }
            }
        }

    if (tid == 0) finish_ticket((int)gridDim.x);
}

extern "C" void kernel_launch(void* const* d_in, const int* in_sizes, int n_in,
                              void* d_out, int out_size, void* d_ws, size_t ws_size,
                              hipStream_t stream) {
    const float* values   = (const float*)d_in[0];
    const int*   kinds    = (const int*)  d_in[1];
    const float* Bmat     = (const float*)d_in[2];
    const float* kind_emb = (const float*)d_in[3];
    const float* W1       = (const float*)d_in[4];
    const float* b1       = (const float*)d_in[5];
    const float* W2       = (const float*)d_in[6];
    const float* b2       = (const float*)d_in[7];
    float* out = (float*)d_out;
    const int T = in_sizes[0];   // 65536

    prep_kernel<<<dim3(80 + NBLK), dim3(256), 0, stream>>>(W1, W2, kinds, T);
    fproj_gemm<<<dim3(T / 64 + NK), dim3(512), 0, stream>>>(values, Bmat, kind_emb,
                                                            b1, b2, out, T);
}

// Round 3
// 120.854 us; speedup vs baseline: 1.2855x; 1.2855x over previous
//
#include <hip/hip_runtime.h>
#include <hip/hip_bf16.h>
#include <math.h>

// FieldTypedProjector: per-token Fourier features -> per-kind 2-layer MLP (exact GELU)
//   out[t] = W2[k]^T gelu(W1[k]^T ff(v_t) + b1[k]) + b2[k] + kind_emb[k]
// R9: REVERT R8's finish_ticket — __threadfence() is an agent-scope fence that
//     emits buffer_wbl2+buffer_inv (full L2 writeback/invalidate) per block;
//     1032 invalidates evicted the packed weights from L2 every block ->
//     fproj 20->74us, MfmaUtil 5.5%, all pipes idle (R8 counters). The 1KB
//     hipMemsetAsync dispatch is restored (proven noise-level in R7).
// Kept from R8: prologue prefetch (GEMM1 B-frags + biases above the sin chain).
// New: GEMM2 B2-frag software pipeline — kt=0 frags issued BEFORE the
//     GELU-pack + __syncthreads (compiler can't hoist loads across the
//     barrier), next-kt frags issued inside the unrolled loop.
// Carried: fused atomic bucketing in prep; M=64/512-thread fproj; cos via
//     sin(x+0.25 rev).

#define NK 8
#define DM 256
#define TMAX 65536     // N*S = 32*2048
#define NBLK 256       // T/256 histogram blocks
#define W1PK 16384     // per-kind packed W1 elements (64*256)
#define W2PK 65536     // per-kind packed W2 elements (256*256)
#define LDSTRIDE 262   // prep slab stride

typedef __attribute__((ext_vector_type(8))) short   s16x8;
typedef __attribute__((ext_vector_type(8))) __bf16  bf16x8;
typedef __attribute__((ext_vector_type(4))) float   f32x4;
typedef __attribute__((ext_vector_type(2))) float   f32x2;

// Static device scratch — rewritten every call (never touches d_ws).
__device__ __align__(16) int g_counts[NK * 32];   // one counter per 128B line
__device__ int   g_bucket[(size_t)NK * TMAX];
__device__ __align__(16) short g_W1p[(size_t)NK * W1PK];
__device__ __align__(16) short g_W2p[(size_t)NK * W2PK];

static __device__ __forceinline__ short f2bf(float f) {
    __hip_bfloat16 h = __float2bfloat16(f);
    return __builtin_bit_cast(short, h);
}

// round-to-nearest-ish bf16 truncation (<=1 ulp bf16)
static __device__ __forceinline__ short pkbf(float f) {
    unsigned u = __builtin_bit_cast(unsigned, f);
    return (short)((u + 0x8000u) >> 16);
}

static __device__ __forceinline__ f32x4 mfma16(s16x8 a, s16x8 b, f32x4 c) {
    return __builtin_amdgcn_mfma_f32_16x16x32_bf16(
        __builtin_bit_cast(bf16x8, a), __builtin_bit_cast(bf16x8, b), c, 0, 0, 0);
}

// tanh-form GELU: x*sigmoid(1.59577(x+0.044715x^3)); |err| vs exact erf ~3e-4
static __device__ __forceinline__ float gelu_fast(float x) {
    float t1 = x * x;
    float m  = fmaf(0.0713548162726f, t1, 1.59576912161f);
    float z  = m * x;
    float e  = __expf(-z);
    return x * __frcp_rn(1.0f + e);
}

// ---------------- kernel A: weight pack (LDS-staged) + atomic bucket scatter --
__global__ __launch_bounds__(256) void prep_kernel(const float* __restrict__ W1,
                                                   const float* __restrict__ W2,
                                                   const int* __restrict__ kinds, int T) {
    const int tid = threadIdx.x;
    const int bid = blockIdx.x;
    if (bid < 80) {
        __shared__ float ld[32 * LDSTRIDE];
        const int isW1 = (bid >= 64);
        int kind, kt;
        if (isW1) { kind = (bid - 64) >> 1; kt = (bid - 64) & 1; }
        else      { kind = bid >> 3;        kt = bid & 7; }
        #pragma unroll
        for (int i = 0; i < 8; ++i) {
            int f = tid + i * 256;
            int row = f >> 6, col = (f & 63) * 4;
            int kk = kt * 32 + row;
            f32x4 v = (f32x4){0.f, 0.f, 0.f, 0.f};
            if (isW1) {
                if (kk < 48) v = *(const f32x4*)(W1 + ((size_t)kind * 48 + kk) * DM + col);
            } else {
                v = *(const f32x4*)(W2 + ((size_t)kind * DM + kk) * DM + col);
            }
            float* dst = &ld[row * LDSTRIDE + col];
            *(f32x2*)dst       = (f32x2){v[0], v[1]};
            *(f32x2*)(dst + 2) = (f32x2){v[2], v[3]};
        }
        __syncthreads();
        short* outp = isW1 ? (g_W1p + (size_t)kind * W1PK) : (g_W2p + (size_t)kind * W2PK);
        #pragma unroll
        for (int i = 0; i < 4; ++i) {
            int g = tid + i * 256;
            int ntile = g >> 6, l = g & 63;
            int kk0 = (l >> 4) * 8, n = ntile * 16 + (l & 15);
            s16x8 v;
            #pragma unroll
            for (int j = 0; j < 8; ++j) v[j] = f2bf(ld[(kk0 + j) * LDSTRIDE + n]);
            *(s16x8*)(outp + ((size_t)(kt * 16 + ntile) * 64 + l) * 8) = v;
        }
    } else {
        __shared__ int wcnt[4][NK];
        __shared__ int base_s[NK];
        const int b = bid - 80;
        const int wave = tid >> 6, lane = tid & 63;
        int t = b * 256 + tid;
        int k = (t < T) ? kinds[t] : -1;
        int rank = 0;
        #pragma unroll
        for (int kk = 0; kk < NK; ++kk) {
            unsigned long long m = __ballot(k == kk);
            if (lane == 0) wcnt[wave][kk] = __popcll(m);
            if (k == kk) rank = __popcll(m & ((1ull << lane) - 1ull));
        }
        __syncthreads();
        if (tid < NK) {
            int ws = 0;
            #pragma unroll
            for (int w = 0; w < 4; ++w) { int c = wcnt[w][tid]; wcnt[w][tid] = ws; ws += c; }
            base_s[tid] = atomicAdd(&g_counts[tid * 32], ws);
        }
        __syncthreads();
        if (k >= 0)
            g_bucket[(size_t)k * T + base_s[k] + wcnt[wave][k] + rank] = t;
    }
}

// ---------------- kernel B: fused MLP, 64-token tile of one kind --------------
__global__ __launch_bounds__(512, 4) void fproj_gemm(
    const float* __restrict__ values, const float* __restrict__ Bmat,
    const float* __restrict__ kind_emb, const float* __restrict__ b1,
    const float* __restrict__ b2, float* __restrict__ out, int T)
{
    // worklist mapping: block -> (kind, 64-token tile)
    int cnts[NK];
    #pragma unroll
    for (int i = 0; i < NK; ++i) cnts[i] = g_counts[i * 32];
    const int bid = blockIdx.x;
    const int tid = threadIdx.x;
    int k = -1, m0 = 0, cum = 0, cnt = 0;
    #pragma unroll
    for (int kk = 0; kk < NK; ++kk) {
        int tk = (cnts[kk] + 63) >> 6;
        if (k < 0 && bid < cum + tk) { k = kk; m0 = (bid - cum) * 64; cnt = cnts[kk]; }
        cum += tk;
    }
    if (k < 0) return;
    const int valid = min(64, cnt - m0);
    const int* buck = g_bucket + (size_t)k * T + m0;

    __shared__ short Hpack[16384];  // h 64x256 bf16, A-frag order: (kt2*4+mt)*512 + l*8 + j

    const int wv   = tid >> 6;          // 0..7, wave covers cols [wv*32, +32)
    const int lane = tid & 63;
    const int quad = lane >> 4;
    const int cl   = lane & 15;

    // ---- prologue prefetch: GEMM1 B-frags + biases issued BEFORE the sin
    // chain so their L2 latency hides under the transcendentals.
    const s16x8* B1p = (const s16x8*)(g_W1p + (size_t)k * W1PK);
    s16x8 bfp[2][2];
    #pragma unroll
    for (int kt = 0; kt < 2; ++kt)
        #pragma unroll
        for (int nt = 0; nt < 2; ++nt) bfp[kt][nt] = B1p[(kt * 16 + wv * 2 + nt) * 64 + lane];
    float bias1[2], addc[2];
    #pragma unroll
    for (int nt = 0; nt < 2; ++nt) {
        int c = wv * 32 + nt * 16 + cl;
        bias1[nt] = b1[k * DM + c];
        addc[nt]  = b2[k * DM + c] + kind_emb[k * DM + c];
    }

    // ---- Fourier features directly in A-frag registers for 4 row groups.
    // a-frag elem j, k-tile kt, row group mt: ff[m = mt*16 + cl][kk = kt*32 + quad*8 + j]
    //   kk<24: sin(2*pi*v*B[kk]); kk<48: cos(2*pi*v*B[kk-24]); else 0
    float vm[4];
    #pragma unroll
    for (int mt = 0; mt < 4; ++mt) {
        int row = mt * 16 + cl;
        vm[mt] = (row < valid) ? values[buck[row]] : 0.0f;
    }
    // per-thread band constants (mt-independent); cos(x)=sin(x+0.25 rev)
    float bb0[8], bb1[8];
    const float add0 = (quad == 3) ? 0.25f : 0.0f;
    #pragma unroll
    for (int j = 0; j < 8; ++j) {
        int b0 = (quad == 3) ? j : quad * 8 + j;       // kt=0: quads 0-2 sin, quad 3 cos
        bb0[j] = Bmat[b0];
        int b1i = min(8 * (quad + 1) + j, 23);         // kt=1: quads 0-1 cos, 2-3 zero
        bb1[j] = Bmat[b1i];
    }
    s16x8 a0[4], a1[4];
    #pragma unroll
    for (int mt = 0; mt < 4; ++mt) {
        float v = vm[mt];
        #pragma unroll
        for (int j = 0; j < 8; ++j) {
            float r0 = __builtin_amdgcn_fractf(fmaf(v, bb0[j], add0));
            a0[mt][j] = pkbf(__builtin_amdgcn_sinf(r0));
            float r1 = __builtin_amdgcn_fractf(fmaf(v, bb1[j], 0.25f));
            float c1 = __builtin_amdgcn_sinf(r1);
            a1[mt][j] = pkbf((quad < 2) ? c1 : 0.0f);
        }
    }

    // ---- GEMM1: [64 x 64] x [64 x 256], wave covers cols [wv*32, +32)
    f32x4 acc[4][2];
    #pragma unroll
    for (int mt = 0; mt < 4; ++mt)
        #pragma unroll
        for (int nt = 0; nt < 2; ++nt) acc[mt][nt] = (f32x4){0.f, 0.f, 0.f, 0.f};
    #pragma unroll
    for (int kt = 0; kt < 2; ++kt) {
        #pragma unroll
        for (int mt = 0; mt < 4; ++mt) {
            s16x8 a = kt ? a1[mt] : a0[mt];
            #pragma unroll
            for (int nt = 0; nt < 2; ++nt) acc[mt][nt] = mfma16(a, bfp[kt][nt], acc[mt][nt]);
        }
    }

    // ---- GEMM2 software pipeline: issue kt=0 B2-frags BEFORE the pack phase
    // and the barrier, so their L2 latency hides under GELU + LDS writes.
    const s16x8* B2p = (const s16x8*)(g_W2p + (size_t)k * W2PK);
    s16x8 bf2[2];
    #pragma unroll
    for (int nt = 0; nt < 2; ++nt) bf2[nt] = B2p[(wv * 2 + nt) * 64 + lane];

    // ---- bias + GELU -> Hpack (A-frag layout for GEMM2)
    // C-layout source: lane holds H[m = mt*16 + quad*4 + r][c = wv*32 + nt*16 + cl]
    #pragma unroll
    for (int nt = 0; nt < 2; ++nt) {
        int c = wv * 32 + nt * 16 + cl;
        int kt2 = c >> 5, q2 = (c >> 3) & 3, j2 = c & 7;
        #pragma unroll
        for (int mt = 0; mt < 4; ++mt) {
            short* hp = Hpack + (kt2 * 4 + mt) * 512 + q2 * 128 + j2;
            #pragma unroll
            for (int r = 0; r < 4; ++r) {
                int m = quad * 4 + r;               // row within 16-row group
                float h = gelu_fast(acc[mt][nt][r] + bias1[nt]);
                hp[m * 8] = pkbf(h);
            }
        }
    }
    __syncthreads();

    // ---- GEMM2: [64 x 256] x [256 x 256], wave covers cols [wv*32, +32)
    f32x4 acc2[4][2];
    #pragma unroll
    for (int mt = 0; mt < 4; ++mt)
        #pragma unroll
        for (int nt = 0; nt < 2; ++nt) acc2[mt][nt] = (f32x4){0.f, 0.f, 0.f, 0.f};
    const s16x8* Hp  = (const s16x8*)Hpack;
    #pragma unroll
    for (int kt = 0; kt < 8; ++kt) {
        s16x8 bfn[2];
        if (kt < 7) {
            #pragma unroll
            for (int nt = 0; nt < 2; ++nt)
                bfn[nt] = B2p[((kt + 1) * 16 + wv * 2 + nt) * 64 + lane];
        }
        s16x8 am[4];
        #pragma unroll
        for (int mt = 0; mt < 4; ++mt) am[mt] = Hp[(kt * 4 + mt) * 64 + lane];
        #pragma unroll
        for (int mt = 0; mt < 4; ++mt)
            #pragma unroll
            for (int nt = 0; nt < 2; ++nt) acc2[mt][nt] = mfma16(am[mt], bf2[nt], acc2[mt][nt]);
        #pragma unroll
        for (int nt = 0; nt < 2; ++nt) bf2[nt] = bfn[nt];
    }

    // ---- epilogue: + b2 + kind_emb, scatter rows to out (nontemporal)
    #pragma unroll
    for (int mt = 0; mt < 4; ++mt)
        #pragma unroll
        for (int r = 0; r < 4; ++r) {
            int row = mt * 16 + quad * 4 + r;
            if (row < valid) {
                size_t ro = (size_t)buck[row] * DM;
                #pragma unroll
                for (int nt = 0; nt < 2; ++nt) {
                    int c = wv * 32 + nt * 16 + cl;
                    __builtin_nontemporal_store(acc2[mt][nt][r] + addc[nt], out + ro + c);
                }
            }
        }
}

extern "C" void kernel_launch(void* const* d_in, const int* in_sizes, int n_in,
                              void* d_out, int out_size, void* d_ws, size_t ws_size,
                              hipStream_t stream) {
    const float* values   = (const float*)d_in[0];
    const int*   kinds    = (const int*)  d_in[1];
    const float* Bmat     = (const float*)d_in[2];
    const float* kind_emb = (const float*)d_in[3];
    const float* W1       = (const float*)d_in[4];
    const float* b1       = (const float*)d_in[5];
    const float* W2       = (const float*)d_in[6];
    const float* b2       = (const float*)d_in[7];
    float* out = (float*)d_out;
    const int T = in_sizes[0];   // 65536

    static void* cnt_addr = nullptr;
    if (!cnt_addr) (void)hipGetSymbolAddress(&cnt_addr, HIP_SYMBOL(g_counts));
    hipMemsetAsync(cnt_addr, 0, sizeof(int) * NK * 32, stream);

    prep_kernel<<<dim3(80 + NBLK), dim3(256), 0, stream>>>(W1, W2, kinds, T);
    fproj_gemm<<<dim3(T / 64 + NK), dim3(512), 0, stream>>>(values, Bmat, kind_emb,
                                                            b1, b2, out, T);
}